// Round 7
// baseline (332.677 us; speedup 1.0000x reference)
//
#include <hip/hip_runtime.h>
#include <hip/hip_bf16.h>

typedef unsigned short ushort_t;
typedef short bf16x8 __attribute__((ext_vector_type(8)));
typedef float f32x4 __attribute__((ext_vector_type(4)));

#define B_ 8
#define N_ 128
#define E_ 16256           // 128*127
#define BE 130048          // 8*E_

__device__ __forceinline__ float eluf(float x) {
    return x > 0.0f ? x : __expf(x) - 1.0f;
}
__device__ __forceinline__ ushort_t f2bf(float f) {
    union { float f; unsigned u; } v; v.f = f;
    return (ushort_t)((v.u + 0x7fffu + ((v.u >> 16) & 1u)) >> 16);
}

// async global->LDS, 16B per lane; LDS dest = wave-uniform base + lane*16.
__device__ __forceinline__ void glds16(void* lds, const void* g) {
    __builtin_amdgcn_global_load_lds(
        (const __attribute__((address_space(1))) unsigned int*)g,
        (__attribute__((address_space(3))) unsigned int*)lds, 16, 0, 0);
}

// img32: chunk c (32k x 256n = 16KB): img[c][n][q'][j] = w[c*32 + (q'^((n>>1)&3))*8 + j][n]
__device__ __forceinline__ void img32_elem(const float* __restrict__ w,
                                           ushort_t* __restrict__ img, int i) {
    int c = i >> 13;  int r = i & 8191;
    int n = r >> 5;   int jq = r & 31;
    int quad = jq >> 3, j = jq & 7;
    int kc = quad ^ ((n >> 1) & 3);
    int k = c * 32 + kc * 8 + j;
    img[i] = f2bf(w[(size_t)k * 256 + n]);
}

// three K=256 weight images: e1w2, W1x (= e2w1 rows 512:768), e2w2
__global__ __launch_bounds__(256) void wprep3(
    const float* __restrict__ wA, ushort_t* __restrict__ iA,
    const float* __restrict__ wB, ushort_t* __restrict__ iB,
    const float* __restrict__ wC, ushort_t* __restrict__ iC)
{
    int gid = blockIdx.x * 256 + threadIdx.x;
    if (gid < 65536)        img32_elem(wA, iA, gid);
    else if (gid < 131072)  img32_elem(wB, iB, gid - 65536);
    else                    img32_elem(wC, iC, gid - 131072);
}

// ---------------- node MLP + edge-projection P, fp32, 4 rows/block ----------------
// h = mlp(in[+in2]);  P[n][j] = h[n] @ wE[j-half] + 0.5*bE[j&255]   (j in [0,512))
template<int K, bool TWOIN>
__global__ __launch_bounds__(512) void node_mlp_p(
    const float* __restrict__ in, const float* __restrict__ in2,
    const float* __restrict__ w1, const float* __restrict__ b1,
    const float* __restrict__ w2, const float* __restrict__ b2,
    const float* __restrict__ wE, const float* __restrict__ bE,
    float* __restrict__ P)
{
    __shared__ float xl[4][K];
    __shared__ float hl[4][256];
    __shared__ float ph[4][256];
    __shared__ float ho[4][256];
    const int r0 = blockIdx.x * 4, t = threadIdx.x;
    const int col = t & 255, hf = t >> 8;
    for (int idx = t; idx < 4 * K; idx += 512) {
        int r = idx / K, k = idx - r * K;
        float v = in[(size_t)(r0 + r) * K + k];
        if (TWOIN) v += in2[(size_t)(r0 + r) * K + k];
        xl[r][k] = v;
    }
    __syncthreads();
    constexpr int KH = K / 2;
    float a[4] = {0.f, 0.f, 0.f, 0.f};
    #pragma unroll 2
    for (int k = hf * KH; k < hf * KH + KH; ++k) {
        const float wv = w1[(size_t)k * 256 + col];
        #pragma unroll
        for (int r = 0; r < 4; ++r) a[r] = fmaf(xl[r][k], wv, a[r]);
    }
    if (hf) {
        #pragma unroll
        for (int r = 0; r < 4; ++r) ph[r][col] = a[r];
    }
    __syncthreads();
    if (!hf) {
        const float bb = b1[col];
        #pragma unroll
        for (int r = 0; r < 4; ++r) hl[r][col] = eluf(a[r] + ph[r][col] + bb);
    }
    __syncthreads();
    float a2[4] = {0.f, 0.f, 0.f, 0.f};
    #pragma unroll 2
    for (int k = hf * 128; k < hf * 128 + 128; ++k) {
        const float wv = w2[(size_t)k * 256 + col];
        #pragma unroll
        for (int r = 0; r < 4; ++r) a2[r] = fmaf(hl[r][k], wv, a2[r]);
    }
    if (hf) {
        #pragma unroll
        for (int r = 0; r < 4; ++r) ph[r][col] = a2[r];
    }
    __syncthreads();
    if (!hf) {
        const float bb = b2[col];
        #pragma unroll
        for (int r = 0; r < 4; ++r) ho[r][col] = eluf(a2[r] + ph[r][col] + bb);
    }
    __syncthreads();
    // P phase: thread t -> output col j = t (r-half j<256 / s-half j>=256)
    const float* wp = wE + (size_t)(t >> 8) * 65536 + (t & 255);
    float p0 = 0.f, p1 = 0.f, p2 = 0.f, p3 = 0.f;
    #pragma unroll 4
    for (int k = 0; k < 256; ++k) {
        const float wv = wp[(size_t)k * 256];
        p0 = fmaf(ho[0][k], wv, p0);
        p1 = fmaf(ho[1][k], wv, p1);
        p2 = fmaf(ho[2][k], wv, p2);
        p3 = fmaf(ho[3][k], wv, p3);
    }
    const float bb = 0.5f * bE[t & 255];
    P[(size_t)(r0 + 0) * 512 + t] = p0 + bb;
    P[(size_t)(r0 + 1) * 512 + t] = p1 + bb;
    P[(size_t)(r0 + 2) * 512 + t] = p2 + bb;
    P[(size_t)(r0 + 3) * 512 + t] = p3 + bb;
}

// ---------------- build 256x256 bf16 A-tile from gathered P rows ----------------
// A[row][c] = elu(P[rcv][c] + P[snd][256+c])  (biases baked into P), XOR LDS layout
__device__ __forceinline__ void build_tile(char* smem, const float* __restrict__ P,
                                           int blockRow, int t)
{
    const int tr = t >> 3;
    const int tc = (t & 7) * 32;
    #pragma unroll
    for (int i = 0; i < 4; ++i) {
        const int row = i * 64 + tr;
        const int rg = blockRow + row;
        const int b = rg / E_; const int e = rg - b * E_;
        const int rcv = e / 127; const int kk = e - rcv * 127;
        const int snd = kk + (kk >= rcv ? 1 : 0);
        const float* pr = P + (size_t)(b * N_ + rcv) * 512 + tc;
        const float* ps = P + (size_t)(b * N_ + snd) * 512 + 256 + tc;
        #pragma unroll
        for (int q = 0; q < 4; ++q) {
            float4 ra = *(const float4*)(pr + q * 8);
            float4 rb = *(const float4*)(pr + q * 8 + 4);
            float4 sa = *(const float4*)(ps + q * 8);
            float4 sb = *(const float4*)(ps + q * 8 + 4);
            bf16x8 w;
            w[0] = (short)f2bf(eluf(ra.x + sa.x));
            w[1] = (short)f2bf(eluf(ra.y + sa.y));
            w[2] = (short)f2bf(eluf(ra.z + sa.z));
            w[3] = (short)f2bf(eluf(ra.w + sa.w));
            w[4] = (short)f2bf(eluf(rb.x + sb.x));
            w[5] = (short)f2bf(eluf(rb.y + sb.y));
            w[6] = (short)f2bf(eluf(rb.z + sb.z));
            w[7] = (short)f2bf(eluf(rb.w + sb.w));
            const int ch = (t & 7) * 4 + q;
            *(bf16x8*)(smem + row * 512 + ((ch ^ (row & 7)) << 4)) = w;
        }
    }
}

// ---------------- edge kernel 1: hid1 tile -> GEMM W2e1 -> segment partials ----------------
__global__ __launch_bounds__(512, 2) void edge1_kernel(
    const float* __restrict__ P1,
    const ushort_t* __restrict__ w2img, const float* __restrict__ b2,   // e1b2
    float* __restrict__ aggp0, float* __restrict__ aggp1)
{
    extern __shared__ char smem[];
    const int t = threadIdx.x;
    const int wid = t >> 6, lane = t & 63, lr = lane & 15, lg = lane >> 4;
    const int wr = wid >> 1, wc = wid & 1;
    const int q4 = (lg ^ ((lr >> 1) & 3)) << 4;
    const int blockRow = blockIdx.x * 256;

    auto stageW = [&](const ushort_t* img, int c, int p) {
        const char* src = (const char*)img + (size_t)c * 16384 + wid * 2048 + lane * 16;
        char* dst = smem + 131072 + p * 16384 + wid * 2048;
        glds16(dst, src);
        glds16(dst + 1024, src + 1024);
    };

    float biasA[8];
    #pragma unroll
    for (int f = 0; f < 8; ++f) biasA[f] = b2[wc * 128 + f * 16 + lr];

    f32x4 acc[4][8];
    #pragma unroll
    for (int m = 0; m < 4; ++m)
        #pragma unroll
        for (int f = 0; f < 8; ++f) acc[m][f] = f32x4{0.f, 0.f, 0.f, 0.f};

    stageW(w2img, 0, 0);                 // hide chunk-0 load under build
    build_tile(smem, P1, blockRow, t);

    for (int c = 0; c < 8; ++c) {
        const int p = c & 1;
        if (c < 7) stageW(w2img, c + 1, p ^ 1);
        __syncthreads();
        const char* Wp = smem + 131072 + p * 16384;
        bf16x8 a[4], b[8];
        const int qh = ((c * 4 + lg) ^ (lr & 7)) << 4;
        #pragma unroll
        for (int m = 0; m < 4; ++m)
            a[m] = *(const bf16x8*)(smem + (wr * 64 + m * 16 + lr) * 512 + qh);
        #pragma unroll
        for (int f = 0; f < 8; ++f)
            b[f] = *(const bf16x8*)(Wp + (wc * 128 + f * 16 + lr) * 64 + q4);
        #pragma unroll
        for (int m = 0; m < 4; ++m)
            #pragma unroll
            for (int f = 0; f < 8; ++f)
                acc[m][f] = __builtin_amdgcn_mfma_f32_16x16x32_bf16(a[m], b[f], acc[m][f], 0, 0, 0);
        __syncthreads();
    }

    // epilogue: segment partial sums only (e1 is recomputed by edge2)
    const int gR0 = blockRow + wr * 64;
    const int sFirst = gR0 / 127;
    const int bk = 127 - (gR0 - sFirst * 127);
    float s0[8], s1[8];
    #pragma unroll
    for (int f = 0; f < 8; ++f) { s0[f] = 0.f; s1[f] = 0.f; }
    #pragma unroll
    for (int m = 0; m < 4; ++m)
        #pragma unroll
        for (int f = 0; f < 8; ++f)
            #pragma unroll
            for (int r = 0; r < 4; ++r) {
                const int row = m * 16 + lg * 4 + r;
                float v = eluf(acc[m][f][r] + biasA[f]);
                if (row < bk) s0[f] += v; else s1[f] += v;
            }
    #pragma unroll
    for (int f = 0; f < 8; ++f) {
        s0[f] += __shfl_xor(s0[f], 16); s0[f] += __shfl_xor(s0[f], 32);
        s1[f] += __shfl_xor(s1[f], 16); s1[f] += __shfl_xor(s1[f], 32);
    }
    float* pt = (float*)(smem + 131072);   // [8 waves][2 segs][128 cols]
    if (lg == 0) {
        #pragma unroll
        for (int f = 0; f < 8; ++f) {
            pt[(wid * 2 + 0) * 128 + f * 16 + lr] = s0[f];
            pt[(wid * 2 + 1) * 128 + f * 16 + lr] = s1[f];
        }
    }
    __syncthreads();
    const int S0 = blockRow / 127;
    const int last = (blockRow + 255) / 127;
    const int cnt = last - S0 + 1;                 // 2 or 3
    for (int task = t; task < cnt * 256; task += 512) {
        const int k = task >> 8;
        const int col = task & 255;
        const int sigma = S0 + k;
        const int wcq = col >> 7, c128 = col & 127;
        float sum = 0.f;
        #pragma unroll
        for (int w2r = 0; w2r < 4; ++w2r) {
            int sf = (blockRow + w2r * 64) / 127;
            int j = sigma - sf;
            if (j == 0 || j == 1)
                sum += pt[((w2r * 2 + wcq) * 2 + j) * 128 + c128];
        }
        const bool startIn = (127 * sigma >= blockRow);
        const bool endIn = (127 * sigma + 127 <= blockRow + 256);
        if (startIn) {
            aggp0[(size_t)sigma * 256 + col] = sum;
            if (endIn) aggp1[(size_t)sigma * 256 + col] = 0.f;
        } else {
            aggp1[(size_t)sigma * 256 + col] = sum;
        }
    }
}

// ---------------- edge kernel 2: fully fused hid1 -> e1 -> xskip GEMM -> hid2 -> out ----------------
__global__ __launch_bounds__(512, 2) void edge2_kernel(
    const float* __restrict__ P1, const float* __restrict__ P2,
    const ushort_t* __restrict__ wAimg, const float* __restrict__ bA,   // W2_e1, e1b2
    const ushort_t* __restrict__ wBimg,                                 // W1x (e2 layer1 xskip)
    const ushort_t* __restrict__ wCimg, const float* __restrict__ bC,   // W2_e2, e2b2
    const float* __restrict__ ow, const float* __restrict__ ob,
    float* __restrict__ out)
{
    extern __shared__ char smem[];
    const int t = threadIdx.x;
    const int wid = t >> 6, lane = t & 63, lr = lane & 15, lg = lane >> 4;
    const int wr = wid >> 1, wc = wid & 1;
    const int q4 = (lg ^ ((lr >> 1) & 3)) << 4;
    const int blockRow = blockIdx.x * 256;

    auto stageW = [&](const ushort_t* img, int c, int p) {
        const char* src = (const char*)img + (size_t)c * 16384 + wid * 2048 + lane * 16;
        char* dst = smem + 131072 + p * 16384 + wid * 2048;
        glds16(dst, src);
        glds16(dst + 1024, src + 1024);
    };

    float biasA[8], biasC[8];
    #pragma unroll
    for (int f = 0; f < 8; ++f) {
        biasA[f] = bA[wc * 128 + f * 16 + lr];
        biasC[f] = bC[wc * 128 + f * 16 + lr];
    }

    f32x4 acc[4][8];
    #pragma unroll
    for (int m = 0; m < 4; ++m)
        #pragma unroll
        for (int f = 0; f < 8; ++f) acc[m][f] = f32x4{0.f, 0.f, 0.f, 0.f};

    auto gemm8 = [&](const ushort_t* img, const ushort_t* nextimg) {
        for (int c = 0; c < 8; ++c) {
            const int p = c & 1;
            if (c < 7) stageW(img, c + 1, p ^ 1);
            else if (nextimg) stageW(nextimg, 0, p ^ 1);
            __syncthreads();
            const char* Wp = smem + 131072 + p * 16384;
            bf16x8 a[4], b[8];
            const int qh = ((c * 4 + lg) ^ (lr & 7)) << 4;
            #pragma unroll
            for (int m = 0; m < 4; ++m)
                a[m] = *(const bf16x8*)(smem + (wr * 64 + m * 16 + lr) * 512 + qh);
            #pragma unroll
            for (int f = 0; f < 8; ++f)
                b[f] = *(const bf16x8*)(Wp + (wc * 128 + f * 16 + lr) * 64 + q4);
            #pragma unroll
            for (int m = 0; m < 4; ++m)
                #pragma unroll
                for (int f = 0; f < 8; ++f)
                    acc[m][f] = __builtin_amdgcn_mfma_f32_16x16x32_bf16(a[m], b[f], acc[m][f], 0, 0, 0);
            __syncthreads();
        }
    };

    // ---- stage A: hid1 -> e1 ----
    stageW(wAimg, 0, 0);
    build_tile(smem, P1, blockRow, t);
    gemm8(wAimg, wBimg);

    // transition A: e1 = elu(acc + bA) -> A-tile (bf16, XOR layout)
    #pragma unroll
    for (int m = 0; m < 4; ++m)
        #pragma unroll
        for (int f = 0; f < 8; ++f) {
            const int col = wc * 128 + f * 16 + lr;
            const int ch = col >> 3;
            #pragma unroll
            for (int r = 0; r < 4; ++r) {
                const int row = wr * 64 + m * 16 + lg * 4 + r;
                float v = eluf(acc[m][f][r] + biasA[f]);
                *(ushort_t*)(smem + row * 512 + ((ch ^ (row & 7)) << 4) + ((col & 7) << 1)) = f2bf(v);
            }
            acc[m][f] = f32x4{0.f, 0.f, 0.f, 0.f};
        }

    // ---- stage B: e1 @ W1x ----
    gemm8(wBimg, wCimg);

    // transition B: hid2 = elu(acc + P2r[rcv] + P2s[snd])  (e2b1 baked into P2)
    #pragma unroll
    for (int m = 0; m < 4; ++m)
        #pragma unroll
        for (int r = 0; r < 4; ++r) {
            const int row = wr * 64 + m * 16 + lg * 4 + r;
            const int rg = blockRow + row;
            const int b = rg / E_; const int e = rg - b * E_;
            const int rcv = e / 127; const int kk = e - rcv * 127;
            const int snd = kk + (kk >= rcv ? 1 : 0);
            const float* pr = P2 + (size_t)(b * N_ + rcv) * 512;
            const float* ps = P2 + (size_t)(b * N_ + snd) * 512 + 256;
            #pragma unroll
            for (int f = 0; f < 8; ++f) {
                const int col = wc * 128 + f * 16 + lr;
                float v = eluf(acc[m][f][r] + pr[col] + ps[col]);
                const int ch = col >> 3;
                *(ushort_t*)(smem + row * 512 + ((ch ^ (row & 7)) << 4) + ((col & 7) << 1)) = f2bf(v);
            }
        }
    #pragma unroll
    for (int m = 0; m < 4; ++m)
        #pragma unroll
        for (int f = 0; f < 8; ++f) acc[m][f] = f32x4{0.f, 0.f, 0.f, 0.f};

    // ---- stage C: hid2 @ W2_e2 ----
    gemm8(wCimg, nullptr);

    // final epilogue: project to [row][2]
    float ow0[8], ow1[8];
    #pragma unroll
    for (int f = 0; f < 8; ++f) {
        int col = wc * 128 + f * 16 + lr;
        ow0[f] = ow[col * 2 + 0];
        ow1[f] = ow[col * 2 + 1];
    }
    float s0[4][4], s1[4][4];
    #pragma unroll
    for (int m = 0; m < 4; ++m)
        #pragma unroll
        for (int r = 0; r < 4; ++r) { s0[m][r] = 0.f; s1[m][r] = 0.f; }
    #pragma unroll
    for (int m = 0; m < 4; ++m)
        #pragma unroll
        for (int f = 0; f < 8; ++f)
            #pragma unroll
            for (int r = 0; r < 4; ++r) {
                float v = eluf(acc[m][f][r] + biasC[f]);
                s0[m][r] = fmaf(v, ow0[f], s0[m][r]);
                s1[m][r] = fmaf(v, ow1[f], s1[m][r]);
            }
    #pragma unroll
    for (int msk = 1; msk <= 8; msk <<= 1)
        #pragma unroll
        for (int m = 0; m < 4; ++m)
            #pragma unroll
            for (int r = 0; r < 4; ++r) {
                s0[m][r] += __shfl_xor(s0[m][r], msk);
                s1[m][r] += __shfl_xor(s1[m][r], msk);
            }
    float* part = (float*)smem;   // [256 rows][2 ch][2 wc] = 4KB (A-tile done)
    if (lr == 0) {
        #pragma unroll
        for (int m = 0; m < 4; ++m)
            #pragma unroll
            for (int r = 0; r < 4; ++r) {
                const int row = wr * 64 + m * 16 + lg * 4 + r;
                part[(row * 2 + 0) * 2 + wc] = s0[m][r];
                part[(row * 2 + 1) * 2 + wc] = s1[m][r];
            }
    }
    __syncthreads();
    const int row = t >> 1, chn = t & 1;
    float val = part[(row * 2 + chn) * 2 + 0] + part[(row * 2 + chn) * 2 + 1] + ob[chn];
    out[(size_t)(blockRow + row) * 2 + chn] = val;
}

extern "C" void kernel_launch(void* const* d_in, const int* in_sizes, int n_in,
                              void* d_out, int out_size, void* d_ws, size_t ws_size,
                              hipStream_t stream)
{
    const float* x    = (const float*)d_in[0];
    const float* n1w1 = (const float*)d_in[3];
    const float* n1b1 = (const float*)d_in[4];
    const float* n1w2 = (const float*)d_in[5];
    const float* n1b2 = (const float*)d_in[6];
    const float* e1w1 = (const float*)d_in[7];
    const float* e1b1 = (const float*)d_in[8];
    const float* e1w2 = (const float*)d_in[9];
    const float* e1b2 = (const float*)d_in[10];
    const float* n2w1 = (const float*)d_in[11];
    const float* n2b1 = (const float*)d_in[12];
    const float* n2w2 = (const float*)d_in[13];
    const float* n2b2 = (const float*)d_in[14];
    const float* e2w1 = (const float*)d_in[15];
    const float* e2b1 = (const float*)d_in[16];
    const float* e2w2 = (const float*)d_in[17];
    const float* e2b2 = (const float*)d_in[18];
    const float* ow   = (const float*)d_in[19];
    const float* ob   = (const float*)d_in[20];

    char* ws = (char*)d_ws;
    float*    P1    = (float*)(ws + 0);                        // [1024][512] f32 = 2MB
    float*    P2    = (float*)(ws + (2u << 20));               // 2MB
    float*    aggp0 = (float*)(ws + (4u << 20));               // 1MB
    float*    aggp1 = (float*)(ws + (5u << 20));               // 1MB
    ushort_t* wAimg = (ushort_t*)(ws + (6u << 20));            // 128KB (e1 layer2)
    ushort_t* wBimg = (ushort_t*)(ws + (6u << 20) + (128u << 10)); // 128KB (W1x)
    ushort_t* wCimg = (ushort_t*)(ws + (6u << 20) + (256u << 10)); // 128KB (e2 layer2)

    float* out = (float*)d_out;

    hipFuncSetAttribute((const void*)edge1_kernel,
                        hipFuncAttributeMaxDynamicSharedMemorySize, 163840);
    hipFuncSetAttribute((const void*)edge2_kernel,
                        hipFuncAttributeMaxDynamicSharedMemorySize, 163840);

    wprep3<<<768, 256, 0, stream>>>(e1w2, wAimg, e2w1 + (size_t)512 * 256, wBimg, e2w2, wCimg);

    node_mlp_p<196, false><<<256, 512, 0, stream>>>(
        x, nullptr, n1w1, n1b1, n1w2, n1b2, e1w1, e1b1, P1);

    edge1_kernel<<<BE / 256, 512, 163840, stream>>>(P1, wAimg, e1b2, aggp0, aggp1);

    node_mlp_p<256, true><<<256, 512, 0, stream>>>(
        aggp0, aggp1, n2w1, n2b1, n2w2, n2b2, e2w1, e2b1, P2);

    edge2_kernel<<<BE / 256, 512, 163840, stream>>>(
        P1, P2, wAimg, e1b2, wBimg, wCimg, e2b2, ow, ob, out);
}

// Round 8
// 229.888 us; speedup vs baseline: 1.4471x; 1.4471x over previous
//
#include <hip/hip_runtime.h>
#include <hip/hip_bf16.h>

typedef unsigned short ushort_t;
typedef short bf16x8 __attribute__((ext_vector_type(8)));
typedef float f32x4 __attribute__((ext_vector_type(4)));

#define B_ 8
#define N_ 128
#define E_ 16256           // 128*127
#define BE 130048          // 8*E_

__device__ __forceinline__ float eluf(float x) {
    return x > 0.0f ? x : __expf(x) - 1.0f;
}
__device__ __forceinline__ ushort_t f2bf(float f) {
    union { float f; unsigned u; } v; v.f = f;
    return (ushort_t)((v.u + 0x7fffu + ((v.u >> 16) & 1u)) >> 16);
}

// async global->LDS, 16B per lane; LDS dest = wave-uniform base + lane*16.
__device__ __forceinline__ void glds16(void* lds, const void* g) {
    __builtin_amdgcn_global_load_lds(
        (const __attribute__((address_space(1))) unsigned int*)g,
        (__attribute__((address_space(3))) unsigned int*)lds, 16, 0, 0);
}

// ---------------- weight image builders ----------------
// img32: chunk c (32k x 256n = 16KB): img[c][n][q'][j] = w[c*32 + (q'^((n>>1)&3))*8 + j][n]
__device__ __forceinline__ void img32_elem(const float* __restrict__ w,
                                           ushort_t* __restrict__ img, int i) {
    int c = i >> 13;  int r = i & 8191;
    int n = r >> 5;   int jq = r & 31;
    int quad = jq >> 3, j = jq & 7;
    int kc = quad ^ ((n >> 1) & 3);
    int k = c * 32 + kc * 8 + j;
    img[i] = f2bf(w[(size_t)k * 256 + n]);
}
// img64: chunk c (64k x 256n = 32KB): img[c][n][u'][j] = w[c*64 + (u'^(n&7))*8 + j][n]
__device__ __forceinline__ void img64_elem(const float* __restrict__ w,
                                           ushort_t* __restrict__ img, int i) {
    int c = i >> 14;  int r = i & 16383;
    int n = r >> 6;   int wdx = r & 63;
    int up = wdx >> 3, j = wdx & 7;
    int u = up ^ (n & 7);
    int k = c * 64 + u * 8 + j;
    img[i] = f2bf(w[(size_t)k * 256 + n]);
}

// wA = e1w2 (img32), wB = W1x = e2w1 rows 512:768 (img64), wC = e2w2 (img32)
__global__ __launch_bounds__(256) void wprep3(
    const float* __restrict__ wA, ushort_t* __restrict__ iA,
    const float* __restrict__ wB, ushort_t* __restrict__ iB,
    const float* __restrict__ wC, ushort_t* __restrict__ iC)
{
    int gid = blockIdx.x * 256 + threadIdx.x;
    if (gid < 65536)        img32_elem(wA, iA, gid);
    else if (gid < 131072)  img64_elem(wB, iB, gid - 65536);
    else                    img32_elem(wC, iC, gid - 131072);
}

// ---------------- node MLP + edge-projection P, fp32, 4 rows/block ----------------
// h = mlp(in[+in2]);  P[n][j] = h[n] @ wE[:,j-half] + 0.5*bE[j&255]   (j in [0,512))
template<int K, bool TWOIN>
__global__ __launch_bounds__(512) void node_mlp_p(
    const float* __restrict__ in, const float* __restrict__ in2,
    const float* __restrict__ w1, const float* __restrict__ b1,
    const float* __restrict__ w2, const float* __restrict__ b2,
    const float* __restrict__ wE, const float* __restrict__ bE,
    float* __restrict__ P)
{
    __shared__ float xl[4][K];
    __shared__ float hl[4][256];
    __shared__ float ph[4][256];
    __shared__ float ho[4][256];
    const int r0 = blockIdx.x * 4, t = threadIdx.x;
    const int col = t & 255, hf = t >> 8;
    for (int idx = t; idx < 4 * K; idx += 512) {
        int r = idx / K, k = idx - r * K;
        float v = in[(size_t)(r0 + r) * K + k];
        if (TWOIN) v += in2[(size_t)(r0 + r) * K + k];
        xl[r][k] = v;
    }
    __syncthreads();
    constexpr int KH = K / 2;
    float a[4] = {0.f, 0.f, 0.f, 0.f};
    #pragma unroll 2
    for (int k = hf * KH; k < hf * KH + KH; ++k) {
        const float wv = w1[(size_t)k * 256 + col];
        #pragma unroll
        for (int r = 0; r < 4; ++r) a[r] = fmaf(xl[r][k], wv, a[r]);
    }
    if (hf) {
        #pragma unroll
        for (int r = 0; r < 4; ++r) ph[r][col] = a[r];
    }
    __syncthreads();
    if (!hf) {
        const float bb = b1[col];
        #pragma unroll
        for (int r = 0; r < 4; ++r) hl[r][col] = eluf(a[r] + ph[r][col] + bb);
    }
    __syncthreads();
    float a2[4] = {0.f, 0.f, 0.f, 0.f};
    #pragma unroll 2
    for (int k = hf * 128; k < hf * 128 + 128; ++k) {
        const float wv = w2[(size_t)k * 256 + col];
        #pragma unroll
        for (int r = 0; r < 4; ++r) a2[r] = fmaf(hl[r][k], wv, a2[r]);
    }
    if (hf) {
        #pragma unroll
        for (int r = 0; r < 4; ++r) ph[r][col] = a2[r];
    }
    __syncthreads();
    if (!hf) {
        const float bb = b2[col];
        #pragma unroll
        for (int r = 0; r < 4; ++r) ho[r][col] = eluf(a2[r] + ph[r][col] + bb);
    }
    __syncthreads();
    // P phase: thread t -> output col j = t (r-half j<256 / s-half j>=256)
    const float* wp = wE + (size_t)(t >> 8) * 65536 + (t & 255);
    float p0 = 0.f, p1 = 0.f, p2 = 0.f, p3 = 0.f;
    #pragma unroll 4
    for (int k = 0; k < 256; ++k) {
        const float wv = wp[(size_t)k * 256];
        p0 = fmaf(ho[0][k], wv, p0);
        p1 = fmaf(ho[1][k], wv, p1);
        p2 = fmaf(ho[2][k], wv, p2);
        p3 = fmaf(ho[3][k], wv, p3);
    }
    const float bb = 0.5f * bE[t & 255];
    P[(size_t)(r0 + 0) * 512 + t] = p0 + bb;
    P[(size_t)(r0 + 1) * 512 + t] = p1 + bb;
    P[(size_t)(r0 + 2) * 512 + t] = p2 + bb;
    P[(size_t)(r0 + 3) * 512 + t] = p3 + bb;
}

// ---------------- edge1: A=elu(P1r+P1s) built in LDS -> GEMM wA -> e1 + partials ----------------
// LDS: A-tile 256x512B XOR layout [0,128K), wA ring 2x16K [128K,160K)
__global__ __launch_bounds__(512, 2) void edge1_kernel(
    const float* __restrict__ P1,
    const ushort_t* __restrict__ wimg, const float* __restrict__ bias,   // e1b2
    ushort_t* __restrict__ eout,
    float* __restrict__ aggp0, float* __restrict__ aggp1)
{
    extern __shared__ char smem[];
    const int t = threadIdx.x;
    const int wid = t >> 6, lane = t & 63, lr = lane & 15, lg = lane >> 4;
    const int wr = wid >> 1, wc = wid & 1;
    const int q4 = (lg ^ ((lr >> 1) & 3)) << 4;
    const int blockRow = blockIdx.x * 256;

    auto stageW = [&](int c, int p) {
        const char* src = (const char*)wimg + (size_t)c * 16384 + wid * 2048 + lane * 16;
        char* dst = smem + 131072 + p * 16384 + wid * 2048;
        glds16(dst, src);
        glds16(dst + 1024, src + 1024);
    };

    float biasA[8];
    #pragma unroll
    for (int f = 0; f < 8; ++f) biasA[f] = bias[wc * 128 + f * 16 + lr];

    f32x4 acc[4][8];
    #pragma unroll
    for (int m = 0; m < 4; ++m)
        #pragma unroll
        for (int f = 0; f < 8; ++f) acc[m][f] = f32x4{0.f, 0.f, 0.f, 0.f};

    stageW(0, 0);
    // ---- build A: wave handles rows [wid*32, wid*32+32); lane covers cols lane*4..+3 ----
    #pragma unroll 4
    for (int j = 0; j < 32; ++j) {
        const int row = wid * 32 + j;
        const int rg = blockRow + row;
        const int b = rg / E_; const int e = rg - b * E_;
        const int rcv = e / 127; const int kk = e - rcv * 127;
        const int snd = kk + (kk >= rcv ? 1 : 0);
        const float4 vr = *(const float4*)(P1 + (size_t)(b * N_ + rcv) * 512 + lane * 4);
        const float4 vs = *(const float4*)(P1 + (size_t)(b * N_ + snd) * 512 + 256 + lane * 4);
        unsigned u0 = (unsigned)f2bf(eluf(vr.x + vs.x)) | ((unsigned)f2bf(eluf(vr.y + vs.y)) << 16);
        unsigned u1 = (unsigned)f2bf(eluf(vr.z + vs.z)) | ((unsigned)f2bf(eluf(vr.w + vs.w)) << 16);
        const int byte = row * 512 + ((((lane >> 1) ^ (row & 7))) << 4) + (lane & 1) * 8;
        *(uint2*)(smem + byte) = make_uint2(u0, u1);
    }
    __syncthreads();

    // ---- GEMM: 8 chunks BK=32, 1 barrier/chunk ----
    for (int c = 0; c < 8; ++c) {
        const int p = c & 1;
        if (c < 7) stageW(c + 1, p ^ 1);
        const char* Wp = smem + 131072 + p * 16384;
        bf16x8 a[4], b[8];
        const int qh = ((c * 4 + lg) ^ (lr & 7)) << 4;
        #pragma unroll
        for (int m = 0; m < 4; ++m)
            a[m] = *(const bf16x8*)(smem + (wr * 64 + m * 16 + lr) * 512 + qh);
        #pragma unroll
        for (int f = 0; f < 8; ++f)
            b[f] = *(const bf16x8*)(Wp + (wc * 128 + f * 16 + lr) * 64 + q4);
        #pragma unroll
        for (int m = 0; m < 4; ++m)
            #pragma unroll
            for (int f = 0; f < 8; ++f)
                acc[m][f] = __builtin_amdgcn_mfma_f32_16x16x32_bf16(a[m], b[f], acc[m][f], 0, 0, 0);
        __syncthreads();
    }

    // ---- epilogue: elu+bias -> slice + e1 store + deterministic segment partials ----
    char* slice = smem + wid * 16384;
    const int gR0 = blockRow + wr * 64;
    const int sFirst = gR0 / 127;
    const int bk = 127 - (gR0 - sFirst * 127);     // local row < bk -> seg sFirst
    float s0[8], s1[8];
    #pragma unroll
    for (int f = 0; f < 8; ++f) { s0[f] = 0.f; s1[f] = 0.f; }
    #pragma unroll
    for (int m = 0; m < 4; ++m)
        #pragma unroll
        for (int f = 0; f < 8; ++f) {
            const int col = f * 16 + lr;         // local 0..127
            const int cc = col >> 3;
            #pragma unroll
            for (int r = 0; r < 4; ++r) {
                const int row = m * 16 + lg * 4 + r;   // local 0..63
                float v = eluf(acc[m][f][r] + biasA[f]);
                *(ushort_t*)(slice + row * 256 + ((cc ^ (row & 7)) << 4) + ((col & 7) << 1)) = f2bf(v);
                if (row < bk) s0[f] += v; else s1[f] += v;
            }
        }
    #pragma unroll
    for (int f = 0; f < 8; ++f) {
        s0[f] += __shfl_xor(s0[f], 16); s0[f] += __shfl_xor(s0[f], 32);
        s1[f] += __shfl_xor(s1[f], 16); s1[f] += __shfl_xor(s1[f], 32);
    }
    float* pt = (float*)(smem + 131072);   // [8 waves][2 segs][128 cols]
    if (lg == 0) {
        #pragma unroll
        for (int f = 0; f < 8; ++f) {
            pt[(wid * 2 + 0) * 128 + f * 16 + lr] = s0[f];
            pt[(wid * 2 + 1) * 128 + f * 16 + lr] = s1[f];
        }
    }
    asm volatile("s_waitcnt lgkmcnt(0)" ::: "memory");
    #pragma unroll
    for (int it = 0; it < 16; ++it) {
        const int q = it * 64 + lane;
        const int row = q >> 4, ccp = q & 15;
        bf16x8 v = *(const bf16x8*)(slice + row * 256 + (ccp << 4));
        const int cc = ccp ^ (row & 7);
        const int grow = blockRow + wr * 64 + row;
        *(bf16x8*)(eout + (size_t)grow * 256 + wc * 128 + cc * 8) = v;
    }
    __syncthreads();
    const int S0 = blockRow / 127;
    const int last = (blockRow + 255) / 127;
    const int cnt = last - S0 + 1;                 // 2 or 3
    for (int task = t; task < cnt * 256; task += 512) {
        const int k = task >> 8;
        const int col = task & 255;
        const int sigma = S0 + k;
        const int wcq = col >> 7, c128 = col & 127;
        float sum = 0.f;
        #pragma unroll
        for (int w2r = 0; w2r < 4; ++w2r) {
            int sf = (blockRow + w2r * 64) / 127;
            int jj = sigma - sf;
            if (jj == 0 || jj == 1)
                sum += pt[((w2r * 2 + wcq) * 2 + jj) * 128 + c128];
        }
        const bool startIn = (127 * sigma >= blockRow);
        const bool endIn = (127 * sigma + 127 <= blockRow + 256);
        if (startIn) {
            aggp0[(size_t)sigma * 256 + col] = sum;
            if (endIn) aggp1[(size_t)sigma * 256 + col] = 0.f;
        } else {
            aggp1[(size_t)sigma * 256 + col] = sum;
        }
    }
}

// ---------------- edge2: e1 @ W1x (BK=64) -> +P2r+P2s, elu -> hid2 @ W2e2 -> project ----------------
// LDS: GEMM1: A ring 2x32K [0,64K), wB ring 2x32K [64K,128K), wC ring [128K,160K)
//      GEMM2: Hid 256x512B [0,128K), wC ring [128K,160K)
__global__ __launch_bounds__(512, 2) void edge2_kernel(
    const ushort_t* __restrict__ e1, const float* __restrict__ P2,
    const ushort_t* __restrict__ wBimg,     // img64, 4 chunks
    const ushort_t* __restrict__ wCimg,     // img32, 8 chunks
    const float* __restrict__ bC,
    const float* __restrict__ ow, const float* __restrict__ ob,
    float* __restrict__ out)
{
    extern __shared__ char smem[];
    const int t = threadIdx.x;
    const int wid = t >> 6, lane = t & 63, lr = lane & 15, lg = lane >> 4;
    const int wr = wid >> 1, wc = wid & 1;
    const int q4 = (lg ^ ((lr >> 1) & 3)) << 4;
    const int blockRow = blockIdx.x * 256;

    // per-lane A row pointers (pre-swizzled 16B-unit offset)
    const int uoff = ((lane & 7) ^ ((lane >> 3) & 7)) * 8;
    const ushort_t* ap[4];
    #pragma unroll
    for (int it = 0; it < 4; ++it) {
        int r = wid * 32 + it * 8 + (lane >> 3);
        ap[it] = e1 + (size_t)(blockRow + r) * 256 + uoff;
    }

    float biasC[8];
    #pragma unroll
    for (int f = 0; f < 8; ++f) biasC[f] = bC[wc * 128 + f * 16 + lr];

    f32x4 acc[4][8];
    #pragma unroll
    for (int m = 0; m < 4; ++m)
        #pragma unroll
        for (int f = 0; f < 8; ++f) acc[m][f] = f32x4{0.f, 0.f, 0.f, 0.f};

    auto stageB64 = [&](int c, int p) {
        const char* src = (const char*)wBimg + (size_t)c * 32768 + wid * 4096 + lane * 16;
        char* dst = smem + 65536 + p * 32768 + wid * 4096;
        #pragma unroll
        for (int it = 0; it < 4; ++it) glds16(dst + it * 1024, src + it * 1024);
    };
    auto stageA64 = [&](int k0, int p) {
        char* dst = smem + p * 32768 + wid * 4096;
        #pragma unroll
        for (int it = 0; it < 4; ++it) glds16(dst + it * 1024, ap[it] + k0);
    };
    auto stageC = [&](int c, int p) {
        const char* src = (const char*)wCimg + (size_t)c * 16384 + wid * 2048 + lane * 16;
        char* dst = smem + 131072 + p * 16384 + wid * 2048;
        glds16(dst, src);
        glds16(dst + 1024, src + 1024);
    };

    // ---- GEMM1: e1 @ W1x, 4 chunks BK=64 ----
    stageB64(0, 0);
    stageA64(0, 0);
    __syncthreads();
    for (int c = 0; c < 4; ++c) {
        const int p = c & 1;
        if (c < 3) { stageB64(c + 1, p ^ 1); stageA64((c + 1) * 64, p ^ 1); }
        else       { stageC(0, 0); }
        const char* Ab = smem + p * 32768;
        const char* Bb = smem + 65536 + p * 32768;
        #pragma unroll
        for (int ks = 0; ks < 2; ++ks) {
            bf16x8 a[4], b[8];
            const int sw = ks * 4 + lg;
            #pragma unroll
            for (int m = 0; m < 4; ++m)
                a[m] = *(const bf16x8*)(Ab + (wr * 64 + m * 16 + lr) * 128 + ((sw ^ (lr & 7)) << 4));
            #pragma unroll
            for (int f = 0; f < 8; ++f)
                b[f] = *(const bf16x8*)(Bb + (wc * 128 + f * 16 + lr) * 128 + ((sw ^ (lr & 7)) << 4));
            #pragma unroll
            for (int m = 0; m < 4; ++m)
                #pragma unroll
                for (int f = 0; f < 8; ++f)
                    acc[m][f] = __builtin_amdgcn_mfma_f32_16x16x32_bf16(a[m], b[f], acc[m][f], 0, 0, 0);
        }
        __syncthreads();
    }

    // ---- transition: hid2 = elu(acc + P2r + P2s) -> Hid (bf16, XOR layout) ----
    #pragma unroll
    for (int m = 0; m < 4; ++m)
        #pragma unroll
        for (int r = 0; r < 4; ++r) {
            const int row = wr * 64 + m * 16 + lg * 4 + r;
            const int rg = blockRow + row;
            const int b = rg / E_; const int e = rg - b * E_;
            const int rcv = e / 127; const int kk = e - rcv * 127;
            const int snd = kk + (kk >= rcv ? 1 : 0);
            const float* pr = P2 + (size_t)(b * N_ + rcv) * 512;
            const float* ps = P2 + (size_t)(b * N_ + snd) * 512 + 256;
            #pragma unroll
            for (int f = 0; f < 8; ++f) {
                const int col = wc * 128 + f * 16 + lr;
                float v = eluf(acc[m][f][r] + pr[col] + ps[col]);
                const int ch = col >> 3;
                *(ushort_t*)(smem + row * 512 + ((ch ^ (row & 7)) << 4) + ((col & 7) << 1)) = f2bf(v);
            }
        }
    #pragma unroll
    for (int m = 0; m < 4; ++m)
        #pragma unroll
        for (int f = 0; f < 8; ++f) acc[m][f] = f32x4{0.f, 0.f, 0.f, 0.f};
    __syncthreads();

    // ---- GEMM2: hid2 @ W2e2, 8 chunks BK=32 ----
    for (int c = 0; c < 8; ++c) {
        const int p = c & 1;
        if (c < 7) stageC(c + 1, p ^ 1);
        const char* Wp = smem + 131072 + p * 16384;
        bf16x8 a[4], b[8];
        const int qh = ((c * 4 + lg) ^ (lr & 7)) << 4;
        #pragma unroll
        for (int m = 0; m < 4; ++m)
            a[m] = *(const bf16x8*)(smem + (wr * 64 + m * 16 + lr) * 512 + qh);
        #pragma unroll
        for (int f = 0; f < 8; ++f)
            b[f] = *(const bf16x8*)(Wp + (wc * 128 + f * 16 + lr) * 64 + q4);
        #pragma unroll
        for (int m = 0; m < 4; ++m)
            #pragma unroll
            for (int f = 0; f < 8; ++f)
                acc[m][f] = __builtin_amdgcn_mfma_f32_16x16x32_bf16(a[m], b[f], acc[m][f], 0, 0, 0);
        __syncthreads();
    }

    // ---- epilogue: fused projection to [row][2] ----
    float ow0[8], ow1[8];
    #pragma unroll
    for (int f = 0; f < 8; ++f) {
        int col = wc * 128 + f * 16 + lr;
        ow0[f] = ow[col * 2 + 0];
        ow1[f] = ow[col * 2 + 1];
    }
    float s0[4][4], s1[4][4];
    #pragma unroll
    for (int m = 0; m < 4; ++m)
        #pragma unroll
        for (int r = 0; r < 4; ++r) { s0[m][r] = 0.f; s1[m][r] = 0.f; }
    #pragma unroll
    for (int m = 0; m < 4; ++m)
        #pragma unroll
        for (int f = 0; f < 8; ++f)
            #pragma unroll
            for (int r = 0; r < 4; ++r) {
                float v = eluf(acc[m][f][r] + biasC[f]);
                s0[m][r] = fmaf(v, ow0[f], s0[m][r]);
                s1[m][r] = fmaf(v, ow1[f], s1[m][r]);
            }
    #pragma unroll
    for (int msk = 1; msk <= 8; msk <<= 1)
        #pragma unroll
        for (int m = 0; m < 4; ++m)
            #pragma unroll
            for (int r = 0; r < 4; ++r) {
                s0[m][r] += __shfl_xor(s0[m][r], msk);
                s1[m][r] += __shfl_xor(s1[m][r], msk);
            }
    float* part = (float*)smem;   // [256 rows][2 ch][2 wc] = 4KB
    if (lr == 0) {
        #pragma unroll
        for (int m = 0; m < 4; ++m)
            #pragma unroll
            for (int r = 0; r < 4; ++r) {
                const int row = wr * 64 + m * 16 + lg * 4 + r;
                part[(row * 2 + 0) * 2 + wc] = s0[m][r];
                part[(row * 2 + 1) * 2 + wc] = s1[m][r];
            }
    }
    __syncthreads();
    const int row = t >> 1, chn = t & 1;
    float val = part[(row * 2 + chn) * 2 + 0] + part[(row * 2 + chn) * 2 + 1] + ob[chn];
    out[(size_t)(blockRow + row) * 2 + chn] = val;
}

extern "C" void kernel_launch(void* const* d_in, const int* in_sizes, int n_in,
                              void* d_out, int out_size, void* d_ws, size_t ws_size,
                              hipStream_t stream)
{
    const float* x    = (const float*)d_in[0];
    const float* n1w1 = (const float*)d_in[3];
    const float* n1b1 = (const float*)d_in[4];
    const float* n1w2 = (const float*)d_in[5];
    const float* n1b2 = (const float*)d_in[6];
    const float* e1w1 = (const float*)d_in[7];
    const float* e1b1 = (const float*)d_in[8];
    const float* e1w2 = (const float*)d_in[9];
    const float* e1b2 = (const float*)d_in[10];
    const float* n2w1 = (const float*)d_in[11];
    const float* n2b1 = (const float*)d_in[12];
    const float* n2w2 = (const float*)d_in[13];
    const float* n2b2 = (const float*)d_in[14];
    const float* e2w1 = (const float*)d_in[15];
    const float* e2b1 = (const float*)d_in[16];
    const float* e2w2 = (const float*)d_in[17];
    const float* e2b2 = (const float*)d_in[18];
    const float* ow   = (const float*)d_in[19];
    const float* ob   = (const float*)d_in[20];

    char* ws = (char*)d_ws;
    ushort_t* wA    = (ushort_t*)(ws + 0);                       // 128 KB (e1w2 img32)
    ushort_t* wB    = (ushort_t*)(ws + (128u << 10));            // 128 KB (W1x img64)
    ushort_t* wC    = (ushort_t*)(ws + (256u << 10));            // 128 KB (e2w2 img32)
    float*    P1    = (float*)(ws + (512u << 10));               // 2 MB  [1024][512]
    float*    P2    = (float*)(ws + (512u << 10) + (2u << 20));  // 2 MB
    float*    aggp0 = (float*)(ws + (512u << 10) + (4u << 20));  // 1 MB  [1024][256]
    float*    aggp1 = (float*)(ws + (512u << 10) + (5u << 20));  // 1 MB
    ushort_t* e1    = (ushort_t*)(ws + (512u << 10) + (6u << 20)); // 66.6 MB [BE][256]

    float* out = (float*)d_out;

    hipFuncSetAttribute((const void*)edge1_kernel,
                        hipFuncAttributeMaxDynamicSharedMemorySize, 163840);
    hipFuncSetAttribute((const void*)edge2_kernel,
                        hipFuncAttributeMaxDynamicSharedMemorySize, 163840);

    wprep3<<<768, 256, 0, stream>>>(e1w2, wA, e2w1 + (size_t)512 * 256, wB, e2w2, wC);

    node_mlp_p<196, false><<<256, 512, 0, stream>>>(
        x, nullptr, n1w1, n1b1, n1w2, n1b2, e1w1, e1b1, P1);

    edge1_kernel<<<BE / 256, 512, 163840, stream>>>(P1, wA, e1b2, e1, aggp0, aggp1);

    node_mlp_p<256, true><<<256, 512, 0, stream>>>(
        aggp0, aggp1, n2w1, n2b1, n2w2, n2b2, e2w1, e2b1, P2);

    edge2_kernel<<<BE / 256, 512, 163840, stream>>>(
        e1, P2, wB, wC, e2b2, ow, ob, out);
}